// Round 1
// baseline (1887.249 us; speedup 1.0000x reference)
//
#include <hip/hip_runtime.h>
#include <math.h>

// Problem constants (match reference)
constexpr int kB   = 4;
constexpr int kNC  = 1024;
constexpr int kNP  = 32768;
constexpr int kK   = 3;
constexpr int kC   = 256;
constexpr int kDIN = 448;
constexpr int kM   = 4;
constexpr int kX   = kC + kDIN;   // 704
constexpr float kEps = 1e-5f;

__device__ __forceinline__ float gelu_exact(float x) {
    return 0.5f * x * (1.0f + erff(x * 0.70710678118654752440f));
}

// ---------------------------------------------------------------------------
// Kernel 1: src = mlp3(pc_embeddings; enc_*) + dense_prompt      (B*NC rows)
// 8 rows per block, 256 threads, thread-per-output-column, LDS row staging.
// ---------------------------------------------------------------------------
__global__ __launch_bounds__(256) void encoder_kernel(
    const float* __restrict__ pc, const float* __restrict__ dense,
    const float* __restrict__ w0, const float* __restrict__ b0,
    const float* __restrict__ w1, const float* __restrict__ b1,
    const float* __restrict__ w2, const float* __restrict__ b2,
    float* __restrict__ src)
{
    constexpr int R = 8;
    __shared__ float xin[R][kDIN];
    __shared__ float h1[R][kC];
    __shared__ float h2[R][kC];
    const int row0 = blockIdx.x * R;
    const int tid = threadIdx.x;

    for (int i = tid; i < R * kDIN; i += 256) {
        int r = i / kDIN, d = i - r * kDIN;
        xin[r][d] = pc[(size_t)(row0 + r) * kDIN + d];
    }
    __syncthreads();

    const int c = tid;
    float acc[R];

    // layer 0: 448 -> 256, relu
    #pragma unroll
    for (int r = 0; r < R; r++) acc[r] = b0[c];
    for (int d4 = 0; d4 < kDIN / 4; d4++) {
        float wv[4];
        #pragma unroll
        for (int j = 0; j < 4; j++) wv[j] = w0[(d4 * 4 + j) * kC + c];
        #pragma unroll
        for (int r = 0; r < R; r++) {
            float4 xv = *reinterpret_cast<const float4*>(&xin[r][d4 * 4]);
            acc[r] = fmaf(xv.x, wv[0], acc[r]);
            acc[r] = fmaf(xv.y, wv[1], acc[r]);
            acc[r] = fmaf(xv.z, wv[2], acc[r]);
            acc[r] = fmaf(xv.w, wv[3], acc[r]);
        }
    }
    #pragma unroll
    for (int r = 0; r < R; r++) h1[r][c] = fmaxf(acc[r], 0.0f);
    __syncthreads();

    // layer 1: 256 -> 256, relu
    #pragma unroll
    for (int r = 0; r < R; r++) acc[r] = b1[c];
    for (int d4 = 0; d4 < kC / 4; d4++) {
        float wv[4];
        #pragma unroll
        for (int j = 0; j < 4; j++) wv[j] = w1[(d4 * 4 + j) * kC + c];
        #pragma unroll
        for (int r = 0; r < R; r++) {
            float4 xv = *reinterpret_cast<const float4*>(&h1[r][d4 * 4]);
            acc[r] = fmaf(xv.x, wv[0], acc[r]);
            acc[r] = fmaf(xv.y, wv[1], acc[r]);
            acc[r] = fmaf(xv.z, wv[2], acc[r]);
            acc[r] = fmaf(xv.w, wv[3], acc[r]);
        }
    }
    #pragma unroll
    for (int r = 0; r < R; r++) h2[r][c] = fmaxf(acc[r], 0.0f);
    __syncthreads();

    // layer 2: 256 -> 256, + dense_prompt
    #pragma unroll
    for (int r = 0; r < R; r++) acc[r] = b2[c];
    for (int d4 = 0; d4 < kC / 4; d4++) {
        float wv[4];
        #pragma unroll
        for (int j = 0; j < 4; j++) wv[j] = w2[(d4 * 4 + j) * kC + c];
        #pragma unroll
        for (int r = 0; r < R; r++) {
            float4 xv = *reinterpret_cast<const float4*>(&h2[r][d4 * 4]);
            acc[r] = fmaf(xv.x, wv[0], acc[r]);
            acc[r] = fmaf(xv.y, wv[1], acc[r]);
            acc[r] = fmaf(xv.z, wv[2], acc[r]);
            acc[r] = fmaf(xv.w, wv[3], acc[r]);
        }
    }
    #pragma unroll
    for (int r = 0; r < R; r++) {
        size_t o = (size_t)(row0 + r) * kC + c;
        src[o] = acc[r] + dense[o];
    }
}

// ---------------------------------------------------------------------------
// Kernel 2: hyper vectors (batch-independent!) + iou_pred (batch-independent).
// Blocks 0..3: hyper chain for token m (store only m>=1). Block 4: iou mlp3.
// ---------------------------------------------------------------------------
__global__ __launch_bounds__(256) void hyper_iou_kernel(
    const float* __restrict__ iou_token, const float* __restrict__ mask_tokens,
    const float* __restrict__ hw0, const float* __restrict__ hb0,
    const float* __restrict__ hw1, const float* __restrict__ hb1,
    const float* __restrict__ hw2, const float* __restrict__ hb2,
    const float* __restrict__ iw0, const float* __restrict__ ib0,
    const float* __restrict__ iw1, const float* __restrict__ ib1,
    const float* __restrict__ iw2, const float* __restrict__ ib2,
    float* __restrict__ hyper_out,   // (3, C)
    float* __restrict__ iou_out)     // (B, 3)
{
    __shared__ float va[kC];
    __shared__ float vb[kC];
    const int tid = threadIdx.x;

    if (blockIdx.x < 4) {
        const int m = blockIdx.x;
        va[tid] = mask_tokens[m * kC + tid];
        __syncthreads();
        const float* W = hw0 + (size_t)m * kC * kC;
        float acc = hb0[m * kC + tid];
        for (int d = 0; d < kC; d++) acc = fmaf(va[d], W[d * kC + tid], acc);
        vb[tid] = fmaxf(acc, 0.0f);
        __syncthreads();
        W = hw1 + (size_t)m * kC * kC;
        acc = hb1[m * kC + tid];
        for (int d = 0; d < kC; d++) acc = fmaf(vb[d], W[d * kC + tid], acc);
        va[tid] = fmaxf(acc, 0.0f);
        __syncthreads();
        W = hw2 + (size_t)m * kC * kC;
        acc = hb2[m * kC + tid];
        for (int d = 0; d < kC; d++) acc = fmaf(va[d], W[d * kC + tid], acc);
        if (m >= 1) hyper_out[(m - 1) * kC + tid] = acc;
    } else {
        va[tid] = iou_token[tid];
        __syncthreads();
        float acc = ib0[tid];
        for (int d = 0; d < kC; d++) acc = fmaf(va[d], iw0[d * 256 + tid], acc);
        vb[tid] = fmaxf(acc, 0.0f);
        __syncthreads();
        acc = ib1[tid];
        for (int d = 0; d < 256; d++) acc = fmaf(vb[d], iw1[d * 256 + tid], acc);
        va[tid] = fmaxf(acc, 0.0f);
        __syncthreads();
        if (tid < kM) {
            acc = ib2[tid];
            for (int d = 0; d < 256; d++) acc = fmaf(va[d], iw2[d * kM + tid], acc);
            if (tid >= 1) {
                for (int b = 0; b < kB; b++) iou_out[b * 3 + (tid - 1)] = acc;
            }
        }
    }
}

// ---------------------------------------------------------------------------
// Kernel 3: fused gather-interp -> concat -> GEMM1 -> LN -> GELU -> GEMM2
//           -> GELU -> 3 hyper dots. 16 rows/block, 256 threads.
// Thread owns one output column; 16 fp32 row-accumulators in registers.
// ---------------------------------------------------------------------------
__global__ __launch_bounds__(256) void main_kernel(
    const float* __restrict__ src,     // (B, NC, C) in ws
    const float* __restrict__ pf,      // (B, NP, DIN)
    const float* __restrict__ iwgt,    // (B, NP, K)
    const int*   __restrict__ iidx,    // (B, NP, K)
    const float* __restrict__ w0, const float* __restrict__ b0,   // (704,256),(256)
    const float* __restrict__ lng, const float* __restrict__ lnb,
    const float* __restrict__ w1, const float* __restrict__ b1,   // (256,256),(256)
    const float* __restrict__ hyper,   // (3, C) in ws
    float* __restrict__ masks)         // (B, 3, NP)
{
    constexpr int R = 16;
    __shared__ float xs[R][kX];        // 45 KB: [interp | pf_feat] tile
    __shared__ float ys[R][kC];        // 16 KB: y tile / u tile
    __shared__ float row_mu[R];
    __shared__ float row_rs[R];

    const int b = blockIdx.y;
    const int p0 = blockIdx.x * R;
    const int tid = threadIdx.x;
    const int c = tid;

    // stage pf_feat -> xs[:, 256:704]
    const float* pfb = pf + ((size_t)b * kNP + p0) * kDIN;
    for (int i = tid; i < R * kDIN; i += 256) {
        int r = i / kDIN, d = i - r * kDIN;
        xs[r][kC + d] = pfb[(size_t)r * kDIN + d];
    }
    // gather-interp -> xs[:, 0:256]   (idx/wgt reads are wave-uniform)
    const float* srcb = src + (size_t)b * kNC * kC;
    const int ibase = (b * kNP + p0) * kK;
    #pragma unroll 4
    for (int r = 0; r < R; r++) {
        float a0 = iwgt[ibase + r * kK + 0];
        float a1 = iwgt[ibase + r * kK + 1];
        float a2 = iwgt[ibase + r * kK + 2];
        int i0 = iidx[ibase + r * kK + 0];
        int i1 = iidx[ibase + r * kK + 1];
        int i2 = iidx[ibase + r * kK + 2];
        xs[r][c] = a0 * srcb[i0 * kC + c] + a1 * srcb[i1 * kC + c] + a2 * srcb[i2 * kC + c];
    }
    __syncthreads();

    // GEMM1: y[r][c] = b0[c] + sum_d xs[r][d] * w0[d][c]
    float acc[R];
    #pragma unroll
    for (int r = 0; r < R; r++) acc[r] = b0[c];
    for (int d4 = 0; d4 < kX / 4; d4++) {
        float wv[4];
        #pragma unroll
        for (int j = 0; j < 4; j++) wv[j] = w0[(d4 * 4 + j) * kC + c];
        #pragma unroll
        for (int r = 0; r < R; r++) {
            float4 xv = *reinterpret_cast<const float4*>(&xs[r][d4 * 4]);
            acc[r] = fmaf(xv.x, wv[0], acc[r]);
            acc[r] = fmaf(xv.y, wv[1], acc[r]);
            acc[r] = fmaf(xv.z, wv[2], acc[r]);
            acc[r] = fmaf(xv.w, wv[3], acc[r]);
        }
    }
    #pragma unroll
    for (int r = 0; r < R; r++) ys[r][c] = acc[r];
    __syncthreads();

    // LayerNorm stats: 16 lanes per row, shuffle reduce (lanes stay in-wave)
    {
        const int r = tid >> 4;
        const int l = tid & 15;
        float s = 0.0f, sq = 0.0f;
        #pragma unroll
        for (int i = 0; i < 16; i++) {
            float v = ys[r][l + 16 * i];
            s += v;
            sq = fmaf(v, v, sq);
        }
        #pragma unroll
        for (int o = 8; o >= 1; o >>= 1) {
            s  += __shfl_xor(s, o);
            sq += __shfl_xor(sq, o);
        }
        if (l == 0) {
            float mu  = s * (1.0f / 256.0f);
            float var = sq * (1.0f / 256.0f) - mu * mu;
            row_mu[r] = mu;
            row_rs[r] = rsqrtf(var + kEps);
        }
    }
    __syncthreads();

    // normalize + gelu -> x2 (reuse xs memory, pitch kC)
    {
        const float g = lng[c], bt = lnb[c];
        float* x2 = &xs[0][0];
        #pragma unroll
        for (int r = 0; r < R; r++) {
            float v = fmaf((ys[r][c] - row_mu[r]) * row_rs[r], g, bt);
            x2[r * kC + c] = gelu_exact(v);
        }
    }
    __syncthreads();

    // GEMM2: u[r][c] = gelu(b1[c] + sum_d x2[r][d] * w1[d][c])
    {
        const float* x2 = &xs[0][0];
        float acc2[R];
        #pragma unroll
        for (int r = 0; r < R; r++) acc2[r] = b1[c];
        for (int d4 = 0; d4 < kC / 4; d4++) {
            float wv[4];
            #pragma unroll
            for (int j = 0; j < 4; j++) wv[j] = w1[(d4 * 4 + j) * kC + c];
            #pragma unroll
            for (int r = 0; r < R; r++) {
                float4 xv = *reinterpret_cast<const float4*>(&x2[r * kC + d4 * 4]);
                acc2[r] = fmaf(xv.x, wv[0], acc2[r]);
                acc2[r] = fmaf(xv.y, wv[1], acc2[r]);
                acc2[r] = fmaf(xv.z, wv[2], acc2[r]);
                acc2[r] = fmaf(xv.w, wv[3], acc2[r]);
            }
        }
        #pragma unroll
        for (int r = 0; r < R; r++) ys[r][c] = gelu_exact(acc2[r]);
    }
    __syncthreads();

    // epilogue: masks[b][m][p0+r] = sum_c hyper[m][c] * u[r][c]
    if (tid < 48) {
        const int m = tid >> 4;    // 0..2
        const int r = tid & 15;    // 0..15
        const float* hy = hyper + m * kC;
        const float* yr = &ys[r][0];
        float dot = 0.0f;
        for (int c4 = 0; c4 < kC / 4; c4++) {
            float4 hv = *reinterpret_cast<const float4*>(&hy[c4 * 4]);
            float4 uv = *reinterpret_cast<const float4*>(&yr[c4 * 4]);
            dot = fmaf(hv.x, uv.x, dot);
            dot = fmaf(hv.y, uv.y, dot);
            dot = fmaf(hv.z, uv.z, dot);
            dot = fmaf(hv.w, uv.w, dot);
        }
        masks[((size_t)b * 3 + m) * kNP + p0 + r] = dot;
    }
}

// ---------------------------------------------------------------------------
extern "C" void kernel_launch(void* const* d_in, const int* in_sizes, int n_in,
                              void* d_out, int out_size, void* d_ws, size_t ws_size,
                              hipStream_t stream) {
    const float* pc_emb  = (const float*)d_in[0];
    // d_in[1] pc_pe, d_in[2] sparse_prompt: dead inputs
    const float* dense   = (const float*)d_in[3];
    const float* pf      = (const float*)d_in[4];
    const float* iwgt    = (const float*)d_in[5];
    const int*   iidx    = (const int*)d_in[6];
    const float* iou_tok = (const float*)d_in[7];
    const float* mtok    = (const float*)d_in[8];
    const float* ew0 = (const float*)d_in[9];
    const float* eb0 = (const float*)d_in[10];
    const float* ew1 = (const float*)d_in[11];
    const float* eb1 = (const float*)d_in[12];
    const float* ew2 = (const float*)d_in[13];
    const float* eb2 = (const float*)d_in[14];
    const float* uw0 = (const float*)d_in[15];
    const float* ub0 = (const float*)d_in[16];
    const float* lng = (const float*)d_in[17];
    const float* lnb = (const float*)d_in[18];
    const float* uw1 = (const float*)d_in[19];
    const float* ub1 = (const float*)d_in[20];
    const float* hw0 = (const float*)d_in[21];
    const float* hb0 = (const float*)d_in[22];
    const float* hw1 = (const float*)d_in[23];
    const float* hb1 = (const float*)d_in[24];
    const float* hw2 = (const float*)d_in[25];
    const float* hb2 = (const float*)d_in[26];
    const float* iw0 = (const float*)d_in[27];
    const float* ib0 = (const float*)d_in[28];
    const float* iw1 = (const float*)d_in[29];
    const float* ib1 = (const float*)d_in[30];
    const float* iw2 = (const float*)d_in[31];
    const float* ib2 = (const float*)d_in[32];

    float* out = (float*)d_out;                       // masks (4,3,32768) then iou (4,3)
    float* ws_src   = (float*)d_ws;                   // (B, NC, C) = 4 MB
    float* ws_hyper = ws_src + (size_t)kB * kNC * kC; // (3, C)

    encoder_kernel<<<kB * kNC / 8, 256, 0, stream>>>(
        pc_emb, dense, ew0, eb0, ew1, eb1, ew2, eb2, ws_src);

    hyper_iou_kernel<<<5, 256, 0, stream>>>(
        iou_tok, mtok, hw0, hb0, hw1, hb1, hw2, hb2,
        iw0, ib0, iw1, ib1, iw2, ib2,
        ws_hyper, out + (size_t)kB * 3 * kNP);

    main_kernel<<<dim3(kNP / 16, kB), 256, 0, stream>>>(
        ws_src, pf, iwgt, iidx, uw0, ub0, lng, lnb, uw1, ub1,
        ws_hyper, out);
}

// Round 2
// 701.777 us; speedup vs baseline: 2.6892x; 2.6892x over previous
//
#include <hip/hip_runtime.h>
#include <math.h>

constexpr int kB   = 4;
constexpr int kNC  = 1024;
constexpr int kNP  = 32768;
constexpr int kC   = 256;
constexpr int kDIN = 448;
constexpr int kM   = 4;

typedef __attribute__((ext_vector_type(8))) short short8;
typedef __attribute__((ext_vector_type(4))) float float4v;

__device__ __forceinline__ float gelu_exact(float x) {
    return 0.5f * x * (1.0f + erff(x * 0.70710678118654752440f));
}
__device__ __forceinline__ unsigned short f2bf(float f) {
    unsigned int u = __float_as_uint(f);
    unsigned int r = (u + 0x7fffu + ((u >> 16) & 1u)) >> 16;
    return (unsigned short)r;
}
__device__ __forceinline__ float bf2f(unsigned short s) {
    return __uint_as_float(((unsigned int)s) << 16);
}

// ---------------------------------------------------------------------------
// Kernel A: fused  (1) encoder mlp3 -> src (bf16)   [blocks 0..511]
//                  (2) hyper chains + iou mlp3       [blocks 512..516]
//                  (3) w0 -> w0s bf16 chunked-transposed [blocks 517..604]
//                  (4) w1 -> w1s bf16 chunked-transposed [blocks 605..636]
// w0s layout: [c=k/32][n=0..255][kk=k%32] bf16  (so staging reads are contiguous)
// ---------------------------------------------------------------------------
__global__ __launch_bounds__(256) void kernelA(
    const float* __restrict__ pc, const float* __restrict__ dense,
    const float* __restrict__ ew0, const float* __restrict__ eb0,
    const float* __restrict__ ew1, const float* __restrict__ eb1,
    const float* __restrict__ ew2, const float* __restrict__ eb2,
    const float* __restrict__ iou_token, const float* __restrict__ mask_tokens,
    const float* __restrict__ hw0, const float* __restrict__ hb0,
    const float* __restrict__ hw1, const float* __restrict__ hb1,
    const float* __restrict__ hw2, const float* __restrict__ hb2,
    const float* __restrict__ iw0, const float* __restrict__ ib0,
    const float* __restrict__ iw1, const float* __restrict__ ib1,
    const float* __restrict__ iw2, const float* __restrict__ ib2,
    const float* __restrict__ uw0, const float* __restrict__ uw1,
    unsigned short* __restrict__ src_bf,   // (B,NC,C) bf16
    float* __restrict__ hyper_out,         // (3,C)
    float* __restrict__ iou_out,           // (B,3)
    unsigned short* __restrict__ w0s,      // 22*256*32 bf16
    unsigned short* __restrict__ w1s)      // 8*256*32 bf16
{
    __shared__ __align__(16) char sm[30720];
    const int tid = threadIdx.x;
    const int bx = blockIdx.x;

    if (bx < 512) {
        // ---------------- encoder: 8 rows/block ----------------
        constexpr int R = 8;
        float* xin = (float*)sm;            // [8][448]
        float* h1  = (float*)(sm + 14336);  // [8][256]
        float* h2  = (float*)(sm + 22528);  // [8][256]
        const int row0 = bx * R;
        for (int i = tid; i < R * kDIN; i += 256) {
            int r = i / kDIN, d = i - r * kDIN;
            xin[r * kDIN + d] = pc[(size_t)(row0 + r) * kDIN + d];
        }
        __syncthreads();
        const int c = tid;
        float acc[R];
        #pragma unroll
        for (int r = 0; r < R; r++) acc[r] = eb0[c];
        for (int d4 = 0; d4 < kDIN / 4; d4++) {
            float wv[4];
            #pragma unroll
            for (int j = 0; j < 4; j++) wv[j] = ew0[(d4 * 4 + j) * kC + c];
            #pragma unroll
            for (int r = 0; r < R; r++) {
                float4 xv = *reinterpret_cast<const float4*>(&xin[r * kDIN + d4 * 4]);
                acc[r] = fmaf(xv.x, wv[0], acc[r]); acc[r] = fmaf(xv.y, wv[1], acc[r]);
                acc[r] = fmaf(xv.z, wv[2], acc[r]); acc[r] = fmaf(xv.w, wv[3], acc[r]);
            }
        }
        #pragma unroll
        for (int r = 0; r < R; r++) h1[r * kC + c] = fmaxf(acc[r], 0.0f);
        __syncthreads();
        #pragma unroll
        for (int r = 0; r < R; r++) acc[r] = eb1[c];
        for (int d4 = 0; d4 < kC / 4; d4++) {
            float wv[4];
            #pragma unroll
            for (int j = 0; j < 4; j++) wv[j] = ew1[(d4 * 4 + j) * kC + c];
            #pragma unroll
            for (int r = 0; r < R; r++) {
                float4 xv = *reinterpret_cast<const float4*>(&h1[r * kC + d4 * 4]);
                acc[r] = fmaf(xv.x, wv[0], acc[r]); acc[r] = fmaf(xv.y, wv[1], acc[r]);
                acc[r] = fmaf(xv.z, wv[2], acc[r]); acc[r] = fmaf(xv.w, wv[3], acc[r]);
            }
        }
        #pragma unroll
        for (int r = 0; r < R; r++) h2[r * kC + c] = fmaxf(acc[r], 0.0f);
        __syncthreads();
        #pragma unroll
        for (int r = 0; r < R; r++) acc[r] = eb2[c];
        for (int d4 = 0; d4 < kC / 4; d4++) {
            float wv[4];
            #pragma unroll
            for (int j = 0; j < 4; j++) wv[j] = ew2[(d4 * 4 + j) * kC + c];
            #pragma unroll
            for (int r = 0; r < R; r++) {
                float4 xv = *reinterpret_cast<const float4*>(&h2[r * kC + d4 * 4]);
                acc[r] = fmaf(xv.x, wv[0], acc[r]); acc[r] = fmaf(xv.y, wv[1], acc[r]);
                acc[r] = fmaf(xv.z, wv[2], acc[r]); acc[r] = fmaf(xv.w, wv[3], acc[r]);
            }
        }
        #pragma unroll
        for (int r = 0; r < R; r++) {
            size_t o = (size_t)(row0 + r) * kC + c;
            src_bf[o] = f2bf(acc[r] + dense[o]);
        }
    } else if (bx < 517) {
        // ---------------- hyper / iou ----------------
        float* va = (float*)sm;
        float* vb = (float*)(sm + 1024);
        if (bx < 516) {
            const int m = bx - 512;
            va[tid] = mask_tokens[m * kC + tid];
            __syncthreads();
            const float* W = hw0 + (size_t)m * kC * kC;
            float acc = hb0[m * kC + tid];
            for (int d = 0; d < kC; d++) acc = fmaf(va[d], W[d * kC + tid], acc);
            vb[tid] = fmaxf(acc, 0.0f);
            __syncthreads();
            W = hw1 + (size_t)m * kC * kC;
            acc = hb1[m * kC + tid];
            for (int d = 0; d < kC; d++) acc = fmaf(vb[d], W[d * kC + tid], acc);
            va[tid] = fmaxf(acc, 0.0f);
            __syncthreads();
            W = hw2 + (size_t)m * kC * kC;
            acc = hb2[m * kC + tid];
            for (int d = 0; d < kC; d++) acc = fmaf(va[d], W[d * kC + tid], acc);
            if (m >= 1) hyper_out[(m - 1) * kC + tid] = acc;
        } else {
            va[tid] = iou_token[tid];
            __syncthreads();
            float acc = ib0[tid];
            for (int d = 0; d < kC; d++) acc = fmaf(va[d], iw0[d * 256 + tid], acc);
            vb[tid] = fmaxf(acc, 0.0f);
            __syncthreads();
            acc = ib1[tid];
            for (int d = 0; d < 256; d++) acc = fmaf(vb[d], iw1[d * 256 + tid], acc);
            va[tid] = fmaxf(acc, 0.0f);
            __syncthreads();
            if (tid < kM) {
                acc = ib2[tid];
                for (int d = 0; d < 256; d++) acc = fmaf(va[d], iw2[d * kM + tid], acc);
                if (tid >= 1)
                    for (int b = 0; b < kB; b++) iou_out[b * 3 + (tid - 1)] = acc;
            }
        }
    } else if (bx < 605) {
        // ---------------- w0 -> w0s ----------------
        int o0 = (bx - 517) * 2048 + tid * 8;
        int c = o0 >> 13, n = (o0 >> 5) & 255, kk = o0 & 31;
        short8 v;
        #pragma unroll
        for (int e = 0; e < 8; e++) {
            int k = c * 32 + kk + e;
            v[e] = (short)f2bf(uw0[k * kC + n]);
        }
        *(short8*)(w0s + o0) = v;
    } else {
        // ---------------- w1 -> w1s ----------------
        int o0 = (bx - 605) * 2048 + tid * 8;
        int c = o0 >> 13, n = (o0 >> 5) & 255, kk = o0 & 31;
        short8 v;
        #pragma unroll
        for (int e = 0; e < 8; e++) {
            int k = c * 32 + kk + e;
            v[e] = (short)f2bf(uw1[k * kC + n]);
        }
        *(short8*)(w1s + o0) = v;
    }
}

// ---------------------------------------------------------------------------
// Main MFMA kernel: 64 rows x 256 cols per block, 4 waves, wave = 64x64
//   GEMM1 (K=704, KC=32): x = [gather-interp | pf_feat] bf16 in LDS
//   LN -> GELU -> x2(bf16) -> GEMM2 (K=256, KC=32) -> GELU -> hyper dots
// ---------------------------------------------------------------------------
constexpr int P  = 40;    // bf16 pitch (80 B): stride 20 dw = 4 mod 8 -> balanced banks
constexpr int P2 = 264;   // x2 pitch (528 B): 132 dw = 4 mod 8

__global__ __launch_bounds__(256, 2) void main_mfma(
    const unsigned short* __restrict__ srcb,   // (B,NC,C) bf16
    const float* __restrict__ pf,
    const float* __restrict__ iwgt,
    const int*   __restrict__ iidx,
    const unsigned short* __restrict__ w0s,    // [22][256][32]
    const unsigned short* __restrict__ w1s,    // [8][256][32]
    const float* __restrict__ b0v, const float* __restrict__ lng,
    const float* __restrict__ lnb, const float* __restrict__ b1v,
    const float* __restrict__ hyper,
    float* __restrict__ masks)
{
    __shared__ __align__(16) char smem[64000];
    unsigned short* xA = (unsigned short*)smem;            // [64][P]
    unsigned short* wA = (unsigned short*)(smem + 5120);   // [256][P]
    unsigned short* x2 = (unsigned short*)smem;            // [64][P2] (union, after GEMM1)
    unsigned short* wB = (unsigned short*)(smem + 33792);  // [256][P]
    float* sums = (float*)(smem + 54272);  // [4][64]
    float* sqs  = (float*)(smem + 55296);  // [4][64]
    float* muA  = (float*)(smem + 56320);  // [64]
    float* rsA  = (float*)(smem + 56576);  // [64]
    float* gg   = (float*)(smem + 56832);  // [256]
    float* bbt  = (float*)(smem + 57856);  // [256]
    float* bb0  = (float*)(smem + 58880);  // [256]
    float* bb1  = (float*)(smem + 59904);  // [256]
    float* hyp  = (float*)(smem + 60928);  // [3][256]
    float* pd   = (float*)(smem + 54272);  // [4][3][64]  (reuse, after LN)

    const int b   = blockIdx.y;
    const int p0  = blockIdx.x * 64;
    const int tid = threadIdx.x;
    const int w = tid >> 6, lane = tid & 63, q = lane >> 4, ml = lane & 15;

    // stage small vectors
    gg[tid]  = lng[tid];
    bbt[tid] = lnb[tid];
    bb0[tid] = b0v[tid];
    bb1[tid] = b1v[tid];
    hyp[tid] = hyper[tid];
    hyp[256 + tid] = hyper[256 + tid];
    hyp[512 + tid] = hyper[512 + tid];

    // staging coordinates: thread owns row sr, k-quarter sk
    const int sr = tid >> 2;
    const int sk = (tid & 3) * 8;

    // gather params for row sr (hoisted)
    const int ibase = (b * kNP + p0 + sr) * 3;
    const float a0 = iwgt[ibase + 0], a1 = iwgt[ibase + 1], a2 = iwgt[ibase + 2];
    const unsigned short* s0 = srcb + ((size_t)b * kNC + iidx[ibase + 0]) * kC;
    const unsigned short* s1 = srcb + ((size_t)b * kNC + iidx[ibase + 1]) * kC;
    const unsigned short* s2 = srcb + ((size_t)b * kNC + iidx[ibase + 2]) * kC;
    const float* pfrow = pf + ((size_t)b * kNP + p0 + sr) * kDIN;

    float4v acc[4][4] = {};

    // ---------------- GEMM1: 22 chunks of K=32 ----------------
    for (int c = 0; c < 22; ++c) {
        if (c < 8) {
            const int k0 = c * 32 + sk;
            #pragma unroll
            for (int j = 0; j < 4; ++j) {
                int kk = k0 + 2 * j;
                unsigned int u0 = *(const unsigned int*)(s0 + kk);
                unsigned int u1 = *(const unsigned int*)(s1 + kk);
                unsigned int u2 = *(const unsigned int*)(s2 + kk);
                float lo = a0 * bf2f((unsigned short)u0) + a1 * bf2f((unsigned short)u1)
                         + a2 * bf2f((unsigned short)u2);
                float hi = a0 * bf2f((unsigned short)(u0 >> 16)) + a1 * bf2f((unsigned short)(u1 >> 16))
                         + a2 * bf2f((unsigned short)(u2 >> 16));
                unsigned int pk = (unsigned int)f2bf(lo) | ((unsigned int)f2bf(hi) << 16);
                *(unsigned int*)((char*)xA + sr * (P * 2) + 2 * (sk + 2 * j)) = pk;
            }
        } else {
            const float* prow = pfrow + (c * 32 - 256) + sk;
            float4 fa = *(const float4*)(prow);
            float4 fb = *(const float4*)(prow + 4);
            short8 v;
            v[0] = (short)f2bf(fa.x); v[1] = (short)f2bf(fa.y);
            v[2] = (short)f2bf(fa.z); v[3] = (short)f2bf(fa.w);
            v[4] = (short)f2bf(fb.x); v[5] = (short)f2bf(fb.y);
            v[6] = (short)f2bf(fb.z); v[7] = (short)f2bf(fb.w);
            *(short8*)(xA + sr * P + sk) = v;
        }
        {
            const uint4* gsrc = (const uint4*)(w0s) + (size_t)(c * 256 + tid) * 4;
            uint4* ldst = (uint4*)(wA + tid * P);
            #pragma unroll
            for (int j = 0; j < 4; ++j) ldst[j] = gsrc[j];
        }
        __syncthreads();
        short8 af[4], bfr[4];
        #pragma unroll
        for (int rt = 0; rt < 4; ++rt) af[rt] = *(const short8*)(xA + (16 * rt + ml) * P + q * 8);
        #pragma unroll
        for (int ct = 0; ct < 4; ++ct) bfr[ct] = *(const short8*)(wA + (64 * w + 16 * ct + ml) * P + q * 8);
        #pragma unroll
        for (int rt = 0; rt < 4; ++rt)
            #pragma unroll
            for (int ct = 0; ct < 4; ++ct)
                acc[rt][ct] = __builtin_amdgcn_mfma_f32_16x16x32_bf16(af[rt], bfr[ct], acc[rt][ct], 0, 0, 0);
        __syncthreads();
    }

    // ---------------- bias + LayerNorm stats ----------------
    {
        float bc[4];
        #pragma unroll
        for (int ct = 0; ct < 4; ++ct) bc[ct] = bb0[64 * w + 16 * ct + ml];
        #pragma unroll
        for (int rt = 0; rt < 4; ++rt)
            #pragma unroll
            for (int ct = 0; ct < 4; ++ct)
                #pragma unroll
                for (int i = 0; i < 4; ++i) acc[rt][ct][i] += bc[ct];
    }
    {
        float s[4][4], s2[4][4];
        #pragma unroll
        for (int rt = 0; rt < 4; ++rt)
            #pragma unroll
            for (int i = 0; i < 4; ++i) {
                float a = 0.f, b2 = 0.f;
                #pragma unroll
                for (int ct = 0; ct < 4; ++ct) {
                    float v = acc[rt][ct][i];
                    a += v; b2 = fmaf(v, v, b2);
                }
                s[rt][i] = a; s2[rt][i] = b2;
            }
        #pragma unroll
        for (int o = 1; o < 16; o <<= 1) {
            #pragma unroll
            for (int rt = 0; rt < 4; ++rt)
                #pragma unroll
                for (int i = 0; i < 4; ++i) {
                    s[rt][i]  += __shfl_xor(s[rt][i], o);
                    s2[rt][i] += __shfl_xor(s2[rt][i], o);
                }
        }
        if (ml == 0) {
            #pragma unroll
            for (int rt = 0; rt < 4; ++rt)
                #pragma unroll
                for (int i = 0; i < 4; ++i) {
                    int row = 16 * rt + 4 * q + i;
                    sums[w * 64 + row] = s[rt][i];
                    sqs[w * 64 + row]  = s2[rt][i];
                }
        }
    }
    __syncthreads();
    if (tid < 64) {
        float ts = sums[tid] + sums[64 + tid] + sums[128 + tid] + sums[192 + tid];
        float tq = sqs[tid] + sqs[64 + tid] + sqs[128 + tid] + sqs[192 + tid];
        float mu = ts * (1.0f / 256.0f);
        float var = tq * (1.0f / 256.0f) - mu * mu;
        muA[tid] = mu;
        rsA[tid] = rsqrtf(var + 1e-5f);
    }
    __syncthreads();

    // ---------------- normalize + GELU -> x2 (bf16) ----------------
    {
        float gc[4], oc[4];
        #pragma unroll
        for (int ct = 0; ct < 4; ++ct) {
            gc[ct] = gg[64 * w + 16 * ct + ml];
            oc[ct] = bbt[64 * w + 16 * ct + ml];
        }
        #pragma unroll
        for (int rt = 0; rt < 4; ++rt)
            #pragma unroll
            for (int i = 0; i < 4; ++i) {
                int row = 16 * rt + 4 * q + i;
                float mu = muA[row], rs = rsA[row];
                #pragma unroll
                for (int ct = 0; ct < 4; ++ct) {
                    float v = (acc[rt][ct][i] - mu) * rs * gc[ct] + oc[ct];
                    x2[row * P2 + 64 * w + 16 * ct + ml] = f2bf(gelu_exact(v));
                }
            }
    }

    // ---------------- GEMM2: 8 chunks of K=32 ----------------
    float4v acc2[4][4] = {};
    for (int c = 0; c < 8; ++c) {
        {
            const uint4* gsrc = (const uint4*)(w1s) + (size_t)(c * 256 + tid) * 4;
            uint4* ldst = (uint4*)(wB + tid * P);
            #pragma unroll
            for (int j = 0; j < 4; ++j) ldst[j] = gsrc[j];
        }
        __syncthreads();
        short8 af[4], bfr[4];
        #pragma unroll
        for (int rt = 0; rt < 4; ++rt) af[rt] = *(const short8*)(x2 + (16 * rt + ml) * P2 + c * 32 + q * 8);
        #pragma unroll
        for (int ct = 0; ct < 4; ++ct) bfr[ct] = *(const short8*)(wB + (64 * w + 16 * ct + ml) * P + q * 8);
        #pragma unroll
        for (int rt = 0; rt < 4; ++rt)
            #pragma unroll
            for (int ct = 0; ct < 4; ++ct)
                acc2[rt][ct] = __builtin_amdgcn_mfma_f32_16x16x32_bf16(af[rt], bfr[ct], acc2[rt][ct], 0, 0, 0);
        __syncthreads();
    }

    // ---------------- GELU + hyper partial dots ----------------
    {
        float bc1[4], hy[3][4];
        #pragma unroll
        for (int ct = 0; ct < 4; ++ct) bc1[ct] = bb1[64 * w + 16 * ct + ml];
        #pragma unroll
        for (int m = 0; m < 3; ++m)
            #pragma unroll
            for (int ct = 0; ct < 4; ++ct) hy[m][ct] = hyp[m * 256 + 64 * w + 16 * ct + ml];
        float pdl[3][4][4] = {};
        #pragma unroll
        for (int rt = 0; rt < 4; ++rt)
            #pragma unroll
            for (int ct = 0; ct < 4; ++ct)
                #pragma unroll
                for (int i = 0; i < 4; ++i) {
                    float u = gelu_exact(acc2[rt][ct][i] + bc1[ct]);
                    #pragma unroll
                    for (int m = 0; m < 3; ++m) pdl[m][rt][i] = fmaf(u, hy[m][ct], pdl[m][rt][i]);
                }
        #pragma unroll
        for (int o = 1; o < 16; o <<= 1) {
            #pragma unroll
            for (int m = 0; m < 3; ++m)
                #pragma unroll
                for (int rt = 0; rt < 4; ++rt)
                    #pragma unroll
                    for (int i = 0; i < 4; ++i)
                        pdl[m][rt][i] += __shfl_xor(pdl[m][rt][i], o);
        }
        if (ml < 3) {
            const int m = ml;
            #pragma unroll
            for (int rt = 0; rt < 4; ++rt)
                #pragma unroll
                for (int i = 0; i < 4; ++i)
                    pd[(w * 3 + m) * 64 + 16 * rt + 4 * q + i] = pdl[m][rt][i];
        }
    }
    __syncthreads();
    if (tid < 192) {
        int m = tid >> 6, r = tid & 63;
        float v = pd[(0 * 3 + m) * 64 + r] + pd[(1 * 3 + m) * 64 + r]
                + pd[(2 * 3 + m) * 64 + r] + pd[(3 * 3 + m) * 64 + r];
        masks[((size_t)b * 3 + m) * kNP + p0 + r] = v;
    }
}

// ---------------------------------------------------------------------------
extern "C" void kernel_launch(void* const* d_in, const int* in_sizes, int n_in,
                              void* d_out, int out_size, void* d_ws, size_t ws_size,
                              hipStream_t stream) {
    const float* pc_emb  = (const float*)d_in[0];
    const float* dense   = (const float*)d_in[3];
    const float* pf      = (const float*)d_in[4];
    const float* iwgt    = (const float*)d_in[5];
    const int*   iidx    = (const int*)d_in[6];
    const float* iou_tok = (const float*)d_in[7];
    const float* mtok    = (const float*)d_in[8];
    const float* ew0 = (const float*)d_in[9];
    const float* eb0 = (const float*)d_in[10];
    const float* ew1 = (const float*)d_in[11];
    const float* eb1 = (const float*)d_in[12];
    const float* ew2 = (const float*)d_in[13];
    const float* eb2 = (const float*)d_in[14];
    const float* uw0 = (const float*)d_in[15];
    const float* ub0 = (const float*)d_in[16];
    const float* lng = (const float*)d_in[17];
    const float* lnb = (const float*)d_in[18];
    const float* uw1 = (const float*)d_in[19];
    const float* ub1 = (const float*)d_in[20];
    const float* hw0 = (const float*)d_in[21];
    const float* hb0 = (const float*)d_in[22];
    const float* hw1 = (const float*)d_in[23];
    const float* hb1 = (const float*)d_in[24];
    const float* hw2 = (const float*)d_in[25];
    const float* hb2 = (const float*)d_in[26];
    const float* iw0 = (const float*)d_in[27];
    const float* ib0 = (const float*)d_in[28];
    const float* iw1 = (const float*)d_in[29];
    const float* ib1 = (const float*)d_in[30];
    const float* iw2 = (const float*)d_in[31];
    const float* ib2 = (const float*)d_in[32];

    float* out = (float*)d_out;   // masks (4,3,32768) then iou (4,3)

    // workspace layout (bytes)
    char* ws = (char*)d_ws;
    unsigned short* src_bf = (unsigned short*)ws;                    // 2,097,152 B
    float* ws_hyper        = (float*)(ws + 2097152);                 // 3,072 B
    unsigned short* w0s    = (unsigned short*)(ws + 2100224);        // 360,448 B
    unsigned short* w1s    = (unsigned short*)(ws + 2460672);        // 131,072 B

    kernelA<<<637, 256, 0, stream>>>(
        pc_emb, dense, ew0, eb0, ew1, eb1, ew2, eb2,
        iou_tok, mtok, hw0, hb0, hw1, hb1, hw2, hb2,
        iw0, ib0, iw1, ib1, iw2, ib2,
        uw0, uw1,
        src_bf, ws_hyper, out + (size_t)kB * 3 * kNP, w0s, w1s);

    main_mfma<<<dim3(kNP / 64, kB), 256, 0, stream>>>(
        src_bf, pf, iwgt, iidx, w0s, w1s,
        ub0, lng, lnb, ub1, ws_hyper, out);
}

// Round 3
// 641.294 us; speedup vs baseline: 2.9429x; 1.0943x over previous
//
#include <hip/hip_runtime.h>
#include <hip/hip_bf16.h>
#include <math.h>

constexpr int kB   = 4;
constexpr int kNC  = 1024;
constexpr int kNP  = 32768;
constexpr int kC   = 256;
constexpr int kDIN = 448;
constexpr int kM   = 4;

typedef __attribute__((ext_vector_type(8))) short short8;
typedef __attribute__((ext_vector_type(4))) float float4v;

__device__ __forceinline__ float gelu_exact(float x) {
    return 0.5f * x * (1.0f + erff(x * 0.70710678118654752440f));
}
__device__ __forceinline__ unsigned short f2bf(float f) {
    unsigned int u = __float_as_uint(f);
    unsigned int r = (u + 0x7fffu + ((u >> 16) & 1u)) >> 16;
    return (unsigned short)r;
}
__device__ __forceinline__ float bf2f(unsigned short s) {
    return __uint_as_float(((unsigned int)s) << 16);
}
// packed f32x2 -> bf16x2 (v_cvt_pk_bf16_f32 on gfx950 via hip_bf16)
__device__ __forceinline__ unsigned int pk_bf16(float lo, float hi) {
    __hip_bfloat162 h = __float22bfloat162_rn(float2{lo, hi});
    union { __hip_bfloat162 h; unsigned int u; } c;
    c.h = h;
    return c.u;
}

// ---------------------------------------------------------------------------
// prep: convert weights to bf16 chunked layout ws[c][n][kk], n in [0,256),
// kk in [0,32). Coalesced reads (256 threads sweep n for each k-row).
// 60 blocks: ew0(14) ew1(8) ew2(8) W0a(8) W0b(14) uw1(8)
// ---------------------------------------------------------------------------
__global__ __launch_bounds__(256) void prep_weights(
    const float* __restrict__ ew0, const float* __restrict__ ew1,
    const float* __restrict__ ew2, const float* __restrict__ uw0,
    const float* __restrict__ uw1,
    unsigned short* __restrict__ ew0s, unsigned short* __restrict__ ew1s,
    unsigned short* __restrict__ ew2s, unsigned short* __restrict__ w0as,
    unsigned short* __restrict__ w0bs, unsigned short* __restrict__ w1s_)
{
    const int bx = blockIdx.x, t = threadIdx.x;
    const float* srcW; int k0; unsigned short* dst;
    if (bx < 14)      { srcW = ew0; k0 = bx * 32;              dst = ew0s + bx * 8192; }
    else if (bx < 22) { srcW = ew1; k0 = (bx - 14) * 32;       dst = ew1s + (bx - 14) * 8192; }
    else if (bx < 30) { srcW = ew2; k0 = (bx - 22) * 32;       dst = ew2s + (bx - 22) * 8192; }
    else if (bx < 38) { srcW = uw0; k0 = (bx - 30) * 32;       dst = w0as + (bx - 30) * 8192; }
    else if (bx < 52) { srcW = uw0; k0 = 256 + (bx - 38) * 32; dst = w0bs + (bx - 38) * 8192; }
    else              { srcW = uw1; k0 = (bx - 52) * 32;       dst = w1s_ + (bx - 52) * 8192; }
    unsigned short v[32];
    #pragma unroll
    for (int kk = 0; kk < 32; ++kk) v[kk] = f2bf(srcW[(size_t)(k0 + kk) * kC + t]);
    #pragma unroll
    for (int j = 0; j < 4; ++j) *(short8*)(dst + t * 32 + j * 8) = *(short8*)(v + j * 8);
}

// ---------------------------------------------------------------------------
// B-fragments loaded straight from global chunked weights (L1/L2-hot).
// ---------------------------------------------------------------------------
__device__ __forceinline__ void gemm_x2_global(
    const unsigned short* __restrict__ x2e, const unsigned short* __restrict__ wsrc,
    int nchunk, int w, int q, int ml, float4v acc[4][4])
{
    const unsigned short* wp[4];
    #pragma unroll
    for (int ct = 0; ct < 4; ++ct) wp[ct] = wsrc + ((64 * w + 16 * ct + ml) * 32 + q * 8);
    for (int c = 0; c < nchunk; ++c) {
        short8 af[4], bfr[4];
        #pragma unroll
        for (int rt = 0; rt < 4; ++rt)
            af[rt] = *(const short8*)(x2e + (16 * rt + ml) * 264 + c * 32 + q * 8);
        #pragma unroll
        for (int ct = 0; ct < 4; ++ct) bfr[ct] = *(const short8*)(wp[ct] + c * 8192);
        #pragma unroll
        for (int rt = 0; rt < 4; ++rt)
            #pragma unroll
            for (int ct = 0; ct < 4; ++ct)
                acc[rt][ct] = __builtin_amdgcn_mfma_f32_16x16x32_bf16(af[rt], bfr[ct], acc[rt][ct], 0, 0, 0);
    }
}

// ---------------------------------------------------------------------------
// kernelA: blocks 0..63 encoder mlp3 (64 rows each) fused with Z = src@W0a+b0
//          blocks 64..67 hyper chains, block 68 iou mlp3
// ---------------------------------------------------------------------------
__global__ __launch_bounds__(256) void kernelA(
    const float* __restrict__ pc, const float* __restrict__ dense,
    const unsigned short* __restrict__ ew0s, const float* __restrict__ eb0,
    const unsigned short* __restrict__ ew1s, const float* __restrict__ eb1,
    const unsigned short* __restrict__ ew2s, const float* __restrict__ eb2,
    const unsigned short* __restrict__ w0as, const float* __restrict__ ub0,
    const float* __restrict__ iou_token, const float* __restrict__ mask_tokens,
    const float* __restrict__ hw0, const float* __restrict__ hb0,
    const float* __restrict__ hw1, const float* __restrict__ hb1,
    const float* __restrict__ hw2, const float* __restrict__ hb2,
    const float* __restrict__ iw0, const float* __restrict__ ib0,
    const float* __restrict__ iw1, const float* __restrict__ ib1,
    const float* __restrict__ iw2, const float* __restrict__ ib2,
    unsigned short* __restrict__ Zbf,      // (B*NC, 256) bf16
    float* __restrict__ hyper_out,         // (3, C)
    float* __restrict__ iou_out)           // (B, 3)
{
    __shared__ unsigned short x2e[64 * 264];   // 33792 B
    __shared__ float va[kC];
    __shared__ float vb[kC];
    const int tid = threadIdx.x, bx = blockIdx.x;

    if (bx < 64) {
        const int row0 = bx * 64;
        const int w = tid >> 6, lane = tid & 63, q = lane >> 4, ml = lane & 15;

        // ---- E0: 448 -> 256, relu ----
        const float* pcr[4];
        #pragma unroll
        for (int rt = 0; rt < 4; ++rt) pcr[rt] = pc + (size_t)(row0 + 16 * rt + ml) * kDIN;
        float4v acc[4][4] = {};
        for (int c = 0; c < 14; ++c) {
            short8 af[4], bfr[4];
            #pragma unroll
            for (int rt = 0; rt < 4; ++rt) {
                float4 f0 = *(const float4*)(pcr[rt] + c * 32 + q * 8);
                float4 f1 = *(const float4*)(pcr[rt] + c * 32 + q * 8 + 4);
                union { short8 s; unsigned int u[4]; } cv;
                cv.u[0] = pk_bf16(f0.x, f0.y); cv.u[1] = pk_bf16(f0.z, f0.w);
                cv.u[2] = pk_bf16(f1.x, f1.y); cv.u[3] = pk_bf16(f1.z, f1.w);
                af[rt] = cv.s;
            }
            #pragma unroll
            for (int ct = 0; ct < 4; ++ct)
                bfr[ct] = *(const short8*)(ew0s + (size_t)c * 8192 + (64 * w + 16 * ct + ml) * 32 + q * 8);
            #pragma unroll
            for (int rt = 0; rt < 4; ++rt)
                #pragma unroll
                for (int ct = 0; ct < 4; ++ct)
                    acc[rt][ct] = __builtin_amdgcn_mfma_f32_16x16x32_bf16(af[rt], bfr[ct], acc[rt][ct], 0, 0, 0);
        }
        {
            float bc[4];
            #pragma unroll
            for (int ct = 0; ct < 4; ++ct) bc[ct] = eb0[64 * w + 16 * ct + ml];
            #pragma unroll
            for (int rt = 0; rt < 4; ++rt)
                #pragma unroll
                for (int i = 0; i < 4; ++i) {
                    int row = 16 * rt + 4 * q + i;
                    #pragma unroll
                    for (int ct = 0; ct < 4; ++ct)
                        x2e[row * 264 + 64 * w + 16 * ct + ml] = f2bf(fmaxf(acc[rt][ct][i] + bc[ct], 0.0f));
                }
        }
        __syncthreads();

        // ---- E1: 256 -> 256, relu ----
        float4v acc2[4][4] = {};
        gemm_x2_global(x2e, ew1s, 8, w, q, ml, acc2);
        __syncthreads();   // all reads of x2e done before overwrite
        {
            float bc[4];
            #pragma unroll
            for (int ct = 0; ct < 4; ++ct) bc[ct] = eb1[64 * w + 16 * ct + ml];
            #pragma unroll
            for (int rt = 0; rt < 4; ++rt)
                #pragma unroll
                for (int i = 0; i < 4; ++i) {
                    int row = 16 * rt + 4 * q + i;
                    #pragma unroll
                    for (int ct = 0; ct < 4; ++ct)
                        x2e[row * 264 + 64 * w + 16 * ct + ml] = f2bf(fmaxf(acc2[rt][ct][i] + bc[ct], 0.0f));
                }
        }
        __syncthreads();

        // ---- E2: 256 -> 256 (linear) + dense_prompt -> src ----
        float4v acc3[4][4] = {};
        gemm_x2_global(x2e, ew2s, 8, w, q, ml, acc3);
        __syncthreads();
        {
            float bc[4];
            #pragma unroll
            for (int ct = 0; ct < 4; ++ct) bc[ct] = eb2[64 * w + 16 * ct + ml];
            #pragma unroll
            for (int rt = 0; rt < 4; ++rt)
                #pragma unroll
                for (int i = 0; i < 4; ++i) {
                    int row = 16 * rt + 4 * q + i;
                    #pragma unroll
                    for (int ct = 0; ct < 4; ++ct) {
                        int col = 64 * w + 16 * ct + ml;
                        float v = acc3[rt][ct][i] + bc[ct] + dense[(size_t)(row0 + row) * kC + col];
                        x2e[row * 264 + col] = f2bf(v);
                    }
                }
        }
        __syncthreads();

        // ---- EZ: Z = src @ W0a + up_b0 -> bf16 global ----
        float4v accZ[4][4] = {};
        gemm_x2_global(x2e, w0as, 8, w, q, ml, accZ);
        {
            float bc[4];
            #pragma unroll
            for (int ct = 0; ct < 4; ++ct) bc[ct] = ub0[64 * w + 16 * ct + ml];
            #pragma unroll
            for (int rt = 0; rt < 4; ++rt)
                #pragma unroll
                for (int i = 0; i < 4; ++i) {
                    int row = 16 * rt + 4 * q + i;
                    #pragma unroll
                    for (int ct = 0; ct < 4; ++ct) {
                        int col = 64 * w + 16 * ct + ml;
                        Zbf[(size_t)(row0 + row) * kC + col] = f2bf(accZ[rt][ct][i] + bc[ct]);
                    }
                }
        }
    } else if (bx < 68) {
        const int m = bx - 64;
        va[tid] = mask_tokens[m * kC + tid];
        __syncthreads();
        const float* W = hw0 + (size_t)m * kC * kC;
        float acc = hb0[m * kC + tid];
        for (int d = 0; d < kC; d++) acc = fmaf(va[d], W[d * kC + tid], acc);
        vb[tid] = fmaxf(acc, 0.0f);
        __syncthreads();
        W = hw1 + (size_t)m * kC * kC;
        acc = hb1[m * kC + tid];
        for (int d = 0; d < kC; d++) acc = fmaf(vb[d], W[d * kC + tid], acc);
        va[tid] = fmaxf(acc, 0.0f);
        __syncthreads();
        W = hw2 + (size_t)m * kC * kC;
        acc = hb2[m * kC + tid];
        for (int d = 0; d < kC; d++) acc = fmaf(va[d], W[d * kC + tid], acc);
        if (m >= 1) hyper_out[(m - 1) * kC + tid] = acc;
    } else {
        va[tid] = iou_token[tid];
        __syncthreads();
        float acc = ib0[tid];
        for (int d = 0; d < kC; d++) acc = fmaf(va[d], iw0[d * 256 + tid], acc);
        vb[tid] = fmaxf(acc, 0.0f);
        __syncthreads();
        acc = ib1[tid];
        for (int d = 0; d < 256; d++) acc = fmaf(vb[d], iw1[d * 256 + tid], acc);
        va[tid] = fmaxf(acc, 0.0f);
        __syncthreads();
        if (tid < kM) {
            acc = ib2[tid];
            for (int d = 0; d < 256; d++) acc = fmaf(va[d], iw2[d * kM + tid], acc);
            if (tid >= 1)
                for (int b = 0; b < kB; b++) iou_out[b * 3 + (tid - 1)] = acc;
        }
    }
}

// ---------------------------------------------------------------------------
// main: 64 rows x 256 cols per block. GEMM1 = pf@W0b (barrier-free, global
// frags) -> +interp via Z-gather epilogue -> LN -> GELU -> x2(LDS) ->
// GEMM2 (barrier-free) -> GELU -> hyper dots.
// ---------------------------------------------------------------------------
__global__ __launch_bounds__(256, 3) void main_mfma(
    const unsigned short* __restrict__ Zbf,
    const float* __restrict__ pf,
    const float* __restrict__ iwgt, const int* __restrict__ iidx,
    const unsigned short* __restrict__ w0bs, const unsigned short* __restrict__ w1s_,
    const float* __restrict__ lng, const float* __restrict__ lnb,
    const float* __restrict__ b1v, const float* __restrict__ hyper,
    float* __restrict__ masks)
{
    __shared__ unsigned short x2[64 * 264];     // 33792
    __shared__ int   gi[64][3];
    __shared__ float gw[64][3];
    __shared__ float sums[4][64];
    __shared__ float sqs[4][64];
    __shared__ float muA[64];
    __shared__ float rsA[64];
    __shared__ float pd[12][64];

    const int b = blockIdx.y, p0 = blockIdx.x * 64, tid = threadIdx.x;
    const int w = tid >> 6, lane = tid & 63, q = lane >> 4, ml = lane & 15;

    if (tid < 192) {
        int r = tid / 3, k = tid - r * 3;
        int base = (b * kNP + p0 + r) * 3 + k;
        gi[r][k] = iidx[base];
        gw[r][k] = iwgt[base];
    }
    __syncthreads();

    // ---------------- GEMM1: y = pf @ W0b (K=448, 14 chunks, NO barriers) ----
    const float* pfr[4];
    #pragma unroll
    for (int rt = 0; rt < 4; ++rt)
        pfr[rt] = pf + ((size_t)b * kNP + p0 + 16 * rt + ml) * kDIN;
    const unsigned short* wbp[4];
    #pragma unroll
    for (int ct = 0; ct < 4; ++ct) wbp[ct] = w0bs + ((64 * w + 16 * ct + ml) * 32 + q * 8);

    float4v acc[4][4] = {};
    for (int c = 0; c < 14; ++c) {
        short8 af[4], bfr[4];
        #pragma unroll
        for (int rt = 0; rt < 4; ++rt) {
            float4 f0 = *(const float4*)(pfr[rt] + c * 32 + q * 8);
            float4 f1 = *(const float4*)(pfr[rt] + c * 32 + q * 8 + 4);
            union { short8 s; unsigned int u[4]; } cv;
            cv.u[0] = pk_bf16(f0.x, f0.y); cv.u[1] = pk_bf16(f0.z, f0.w);
            cv.u[2] = pk_bf16(f1.x, f1.y); cv.u[3] = pk_bf16(f1.z, f1.w);
            af[rt] = cv.s;
        }
        #pragma unroll
        for (int ct = 0; ct < 4; ++ct) bfr[ct] = *(const short8*)(wbp[ct] + c * 8192);
        #pragma unroll
        for (int rt = 0; rt < 4; ++rt)
            #pragma unroll
            for (int ct = 0; ct < 4; ++ct)
                acc[rt][ct] = __builtin_amdgcn_mfma_f32_16x16x32_bf16(af[rt], bfr[ct], acc[rt][ct], 0, 0, 0);
    }

    // ---------------- interp add via Z-gather (output space, fp32) ----------
    {
        const unsigned short* zb = Zbf + (size_t)b * kNC * kC;
        #pragma unroll
        for (int rt = 0; rt < 4; ++rt)
            #pragma unroll
            for (int i = 0; i < 4; ++i) {
                int row = 16 * rt + 4 * q + i;
                #pragma unroll
                for (int k = 0; k < 3; ++k) {
                    float wk = gw[row][k];
                    const unsigned short* zr = zb + (size_t)gi[row][k] * kC + 64 * w + ml;
                    #pragma unroll
                    for (int ct = 0; ct < 4; ++ct)
                        acc[rt][ct][i] = fmaf(wk, bf2f(zr[16 * ct]), acc[rt][ct][i]);
                }
            }
    }

    // ---------------- LayerNorm stats ----------------
    {
        float s[4][4], s2[4][4];
        #pragma unroll
        for (int rt = 0; rt < 4; ++rt)
            #pragma unroll
            for (int i = 0; i < 4; ++i) {
                float a = 0.f, b2 = 0.f;
                #pragma unroll
                for (int ct = 0; ct < 4; ++ct) {
                    float v = acc[rt][ct][i];
                    a += v; b2 = fmaf(v, v, b2);
                }
                s[rt][i] = a; s2[rt][i] = b2;
            }
        #pragma unroll
        for (int o = 1; o < 16; o <<= 1) {
            #pragma unroll
            for (int rt = 0; rt < 4; ++rt)
                #pragma unroll
                for (int i = 0; i < 4; ++i) {
                    s[rt][i]  += __shfl_xor(s[rt][i], o);
                    s2[rt][i] += __shfl_xor(s2[rt][i], o);
                }
        }
        if (ml == 0) {
            #pragma unroll
            for (int rt = 0; rt < 4; ++rt)
                #pragma unroll
                for (int i = 0; i < 4; ++i) {
                    int row = 16 * rt + 4 * q + i;
                    sums[w][row] = s[rt][i];
                    sqs[w][row]  = s2[rt][i];
                }
        }
    }
    __syncthreads();
    if (tid < 64) {
        float ts = sums[0][tid] + sums[1][tid] + sums[2][tid] + sums[3][tid];
        float tq = sqs[0][tid] + sqs[1][tid] + sqs[2][tid] + sqs[3][tid];
        float mu = ts * (1.0f / 256.0f);
        float var = tq * (1.0f / 256.0f) - mu * mu;
        muA[tid] = mu;
        rsA[tid] = rsqrtf(var + 1e-5f);
    }
    __syncthreads();

    // ---------------- normalize + GELU -> x2 (bf16, LDS) ----------------
    {
        float gc[4], oc[4];
        #pragma unroll
        for (int ct = 0; ct < 4; ++ct) {
            gc[ct] = lng[64 * w + 16 * ct + ml];
            oc[ct] = lnb[64 * w + 16 * ct + ml];
        }
        #pragma unroll
        for (int rt = 0; rt < 4; ++rt)
            #pragma unroll
            for (int i = 0; i < 4; ++i) {
                int row = 16 * rt + 4 * q + i;
                float mu = muA[row], rs = rsA[row];
                #pragma unroll
                for (int ct = 0; ct < 4; ++ct) {
                    float v = (acc[rt][ct][i] - mu) * rs * gc[ct] + oc[ct];
                    x2[row * 264 + 64 * w + 16 * ct + ml] = f2bf(gelu_exact(v));
                }
            }
    }
    __syncthreads();

    // ---------------- GEMM2: K=256, 8 chunks, NO barriers ----------------
    float4v acc2[4][4] = {};
    gemm_x2_global(x2, w1s_, 8, w, q, ml, acc2);

    // ---------------- GELU + hyper partial dots ----------------
    {
        float bc1[4], hy[3][4];
        #pragma unroll
        for (int ct = 0; ct < 4; ++ct) bc1[ct] = b1v[64 * w + 16 * ct + ml];
        #pragma unroll
        for (int m = 0; m < 3; ++m)
            #pragma unroll
            for (int ct = 0; ct < 4; ++ct) hy[m][ct] = hyper[m * kC + 64 * w + 16 * ct + ml];
        float pdl[3][4][4] = {};
        #pragma unroll
        for (int rt = 0; rt < 4; ++rt)
            #pragma unroll
            for (int ct = 0; ct < 4; ++ct)
                #pragma unroll
                for (int i = 0; i < 4; ++i) {
                    float u = gelu_exact(acc2[rt][ct][i] + bc1[ct]);
                    #pragma unroll
                    for (int m = 0; m < 3; ++m) pdl[m][rt][i] = fmaf(u, hy[m][ct], pdl[m][rt][i]);
                }
        #pragma unroll
        for (int o = 1; o < 16; o <<= 1) {
            #pragma unroll
            for (int m = 0; m < 3; ++m)
                #pragma unroll
                for (int rt = 0; rt < 4; ++rt)
                    #pragma unroll
                    for (int i = 0; i < 4; ++i)
                        pdl[m][rt][i] += __shfl_xor(pdl[m][rt][i], o);
        }
        if (ml < 3) {
            const int m = ml;
            #pragma unroll
            for (int rt = 0; rt < 4; ++rt)
                #pragma unroll
                for (int i = 0; i < 4; ++i)
                    pd[w * 3 + m][16 * rt + 4 * q + i] = pdl[m][rt][i];
        }
    }
    __syncthreads();
    if (tid < 192) {
        int m = tid >> 6, r = tid & 63;
        float v = pd[0 + m][r] + pd[3 + m][r] + pd[6 + m][r] + pd[9 + m][r];
        masks[((size_t)b * 3 + m) * kNP + p0 + r] = v;
    }
}

// ---------------------------------------------------------------------------
extern "C" void kernel_launch(void* const* d_in, const int* in_sizes, int n_in,
                              void* d_out, int out_size, void* d_ws, size_t ws_size,
                              hipStream_t stream) {
    const float* pc_emb  = (const float*)d_in[0];
    const float* dense   = (const float*)d_in[3];
    const float* pf      = (const float*)d_in[4];
    const float* iwgt    = (const float*)d_in[5];
    const int*   iidx    = (const int*)d_in[6];
    const float* iou_tok = (const float*)d_in[7];
    const float* mtok    = (const float*)d_in[8];
    const float* ew0 = (const float*)d_in[9];
    const float* eb0 = (const float*)d_in[10];
    const float* ew1 = (const float*)d_in[11];
    const float* eb1 = (const float*)d_in[12];
    const float* ew2 = (const float*)d_in[13];
    const float* eb2 = (const float*)d_in[14];
    const float* uw0 = (const float*)d_in[15];
    const float* ub0 = (const float*)d_in[16];
    const float* lng = (const float*)d_in[17];
    const float* lnb = (const float*)d_in[18];
    const float* uw1 = (const float*)d_in[19];
    const float* ub1 = (const float*)d_in[20];
    const float* hw0 = (const float*)d_in[21];
    const float* hb0 = (const float*)d_in[22];
    const float* hw1 = (const float*)d_in[23];
    const float* hb1 = (const float*)d_in[24];
    const float* hw2 = (const float*)d_in[25];
    const float* hb2 = (const float*)d_in[26];
    const float* iw0 = (const float*)d_in[27];
    const float* ib0 = (const float*)d_in[28];
    const float* iw1 = (const float*)d_in[29];
    const float* ib1 = (const float*)d_in[30];
    const float* iw2 = (const float*)d_in[31];
    const float* ib2 = (const float*)d_in[32];

    float* out = (float*)d_out;   // masks (4,3,32768) then iou (4,3)

    // workspace layout (bytes)
    char* ws = (char*)d_ws;
    unsigned short* Zbf  = (unsigned short*)(ws + 0);        // 2,097,152
    float* ws_hyper      = (float*)(ws + 2097152);           // 3,072
    unsigned short* ew0s = (unsigned short*)(ws + 2100224);  // 229,376
    unsigned short* ew1s = (unsigned short*)(ws + 2329600);  // 131,072
    unsigned short* ew2s = (unsigned short*)(ws + 2460672);  // 131,072
    unsigned short* w0as = (unsigned short*)(ws + 2591744);  // 131,072
    unsigned short* w0bs = (unsigned short*)(ws + 2722816);  // 229,376
    unsigned short* w1s_ = (unsigned short*)(ws + 2952192);  // 131,072

    prep_weights<<<60, 256, 0, stream>>>(ew0, ew1, ew2, uw0, uw1,
                                         ew0s, ew1s, ew2s, w0as, w0bs, w1s_);

    kernelA<<<69, 256, 0, stream>>>(
        pc_emb, dense, ew0s, eb0, ew1s, eb1, ew2s, eb2, w0as, ub0,
        iou_tok, mtok, hw0, hb0, hw1, hb1, hw2, hb2,
        iw0, ib0, iw1, ib1, iw2, ib2,
        Zbf, ws_hyper, out + (size_t)kB * 3 * kNP);

    main_mfma<<<dim3(kNP / 64, kB), 256, 0, stream>>>(
        Zbf, pf, iwgt, iidx, w0bs, w1s_,
        lng, lnb, ub1, ws_hyper, out);
}